// Round 6
// baseline (427.640 us; speedup 1.0000x reference)
//
#include <hip/hip_runtime.h>
#include <math.h>

typedef _Float16 f16x8 __attribute__((ext_vector_type(8)));
typedef _Float16 f16x2 __attribute__((ext_vector_type(2)));
typedef float    f32x4 __attribute__((ext_vector_type(4)));

constexpr int kT    = 512;   // sequence length
constexpr int kH    = 16;    // hidden
constexpr int kL    = 8;     // layers
constexpr int kG    = 64;    // gates
constexpr int kNB   = 8;     // batch per block
constexpr int kPad  = 24;    // f16 row stride (48 B)
constexpr int kRows = 9;     // 8 batch rows + permanent zero row
constexpr int kSlots= 16;    // ring depth per layer (skew elasticity)
constexpr int kLyr  = kL + 1;               // lyr 0 = x, lyr 1+l = layer l h
constexpr int kSE   = kLyr * kRows * kPad;  // f16 elems per slot (1944)
constexpr int kNW   = 4;     // waves per block (2 layers each)
constexpr int kIB   = 65;    // 65*8 = 520 iterations >= kT+kL-1

constexpr float kL2E = 1.4426950408889634f;

__device__ __forceinline__ float swz8(float v) {   // lane ^ 8 (BitMode)
    return __int_as_float(__builtin_amdgcn_ds_swizzle(__float_as_int(v), 0x201F));
}
__device__ __forceinline__ float sigm2(float z) {  // 1/(1+2^z)
    return __builtin_amdgcn_rcpf(1.0f + __builtin_amdgcn_exp2f(z));
}
__device__ __forceinline__ void cbar() { asm volatile("" ::: "memory"); }

// 4 waves (1 per SIMD), each owns 2 adjacent layers; layer 2w+1's input is
// produced in-wave (no sync). Cross-wave producer-consumer flags + 16-slot
// per-layer h rings. Gate-packed MFMA math identical to rounds 4/5.
__global__ __launch_bounds__(256, 1)
void lstm_pair(const float* __restrict__ x,
               const float* __restrict__ Wih, const float* __restrict__ Whh,
               const float* __restrict__ bih, const float* __restrict__ bhh,
               const float* __restrict__ Wp,  const float* __restrict__ bpos,
               const float* __restrict__ Wo,  const float* __restrict__ bori,
               float* __restrict__ out)
{
    const int tid  = threadIdx.x;
    const int w    = tid >> 6;          // wave 0..3
    const int lane = tid & 63;
    const int n    = lane & 15;
    const int q    = lane >> 4;
    const int bn   = n & 7;
    const bool cLow = (n < 8);
    const bool bact = ((q >> 1) == (n >> 3));
    const int lA   = 2 * w;
    const int lB   = 2 * w + 1;

    __shared__ __align__(16) _Float16 hb[kSlots][kLyr][kRows][kPad];  // 62208 B
    __shared__ int cnt[kNW];

    {   // zero-init LDS; counters to -1
        int* hz = (int*)&hb[0][0][0][0];
        for (int i = tid; i < (int)(sizeof(hb) / 4); i += 256) hz[i] = 0;
        if (tid < kNW) cnt[tid] = -1;
    }

    // ---- A fragments (gate-packed) for both layers ----
    auto loadA = [&](const float* W, int l, int rLow, int rHigh) -> f16x8 {
        const int row = (q < 2) ? (rLow + n) : (rHigh + n);
        const float* src = W + (size_t)l * kG * kH + row * kH + (q & 1) * 8;
        f16x8 a;
        #pragma unroll
        for (int j = 0; j < 8; ++j) a[j] = (_Float16)src[j];
        return a;
    };
    const f16x8 A1P1a = loadA(Wih, lA, 0, 16), A2P1a = loadA(Whh, lA, 0, 16);
    const f16x8 A1P2a = loadA(Wih, lA, 32, 48), A2P2a = loadA(Whh, lA, 32, 48);
    const f16x8 A1P1b = loadA(Wih, lB, 0, 16), A2P1b = loadA(Whh, lB, 0, 16);
    const f16x8 A1P2b = loadA(Wih, lB, 32, 48), A2P2b = loadA(Whh, lB, 32, 48);

    // ---- biases folded into activation arg ----
    const float ank2 = cLow ? (-2.0f * kL2E) : (-kL2E);
    const float am2  = cLow ? 2.0f : 1.0f;
    const float ams2 = cLow ? -1.0f : 0.0f;
    float abk1a[4], abk2a[4], abk1b[4], abk2b[4];
    #pragma unroll
    for (int r = 0; r < 4; ++r) {
        const int u = q * 4 + r;
        const int g1a = lA * kG + (cLow ? u : 16 + u);
        const int g2a = lA * kG + (cLow ? 32 + u : 48 + u);
        const int g1b = lB * kG + (cLow ? u : 16 + u);
        const int g2b = lB * kG + (cLow ? 32 + u : 48 + u);
        abk1a[r] = -kL2E * (bih[g1a] + bhh[g1a]);
        abk2a[r] = ank2  * (bih[g2a] + bhh[g2a]);
        abk1b[r] = -kL2E * (bih[g1b] + bhh[g1b]);
        abk2b[r] = ank2  * (bih[g2b] + bhh[g2b]);
    }

    // ---- LDS base pointers (slot 0; ring slot adds elems) ----
    const int boff = (bact ? bn * kPad : 8 * kPad) + (q & 1) * 8;
    const _Float16* b1a = &hb[0][lA    ][0][0] + boff;   // layer A input
    const _Float16* b2a = &hb[0][lA + 1][0][0] + boff;   // layer A own h
    const _Float16* b1b = &hb[0][lB    ][0][0] + boff;   // layer B input (in-wave)
    const _Float16* b2b = &hb[0][lB + 1][0][0] + boff;   // layer B own h
    _Float16* hwa = &hb[0][lA + 1][bn][q * 4 + (cLow ? 0 : 2)];
    _Float16* hwb = &hb[0][lB + 1][bn][q * 4 + (cLow ? 0 : 2)];
    _Float16* xw  = &hb[0][0][lane >> 3][(lane & 7) * 2];

    // ---- x staging (wave 0): prime x(0) -> slot 15, prefetch x(1) ----
    const float* xg_ptr =
        x + ((size_t)(blockIdx.x * kNB + (lane >> 3)) * kT) * kH + (lane & 7) * 2;
    float xg0 = 0.f, xg1 = 0.f;
    if (w == 0) {
        float2 v0 = *(const float2*)(xg_ptr);
        hb[15][0][lane >> 3][(lane & 7) * 2]     = (_Float16)v0.x;
        hb[15][0][lane >> 3][(lane & 7) * 2 + 1] = (_Float16)v0.y;
        float2 v1 = *(const float2*)(xg_ptr + kH);
        xg0 = v1.x; xg1 = v1.y;
    }

    float c0a = 0.f, c1a = 0.f, c0b = 0.f, c1b = 0.f;
    __syncthreads();    // init visible; last barrier until the head

    const f32x4 zeroC = {0.f, 0.f, 0.f, 0.f};
    volatile const int* upc = (w > 0)       ? &cnt[w - 1] : nullptr;
    volatile const int* dnc = (w < kNW - 1) ? &cnt[w + 1] : nullptr;

    auto lstep = [&](const f16x8& A1P1, const f16x8& A2P1,
                     const f16x8& A1P2, const f16x8& A2P2,
                     const float* abk1, const float* abk2,
                     const _Float16* b1, const _Float16* b2, _Float16* hw,
                     float& c0, float& c1, int roff, int woff, bool active) {
        const f16x8 B1 = *(const f16x8*)(b1 + roff);
        const f16x8 B2 = *(const f16x8*)(b2 + roff);
        f32x4 d1 = __builtin_amdgcn_mfma_f32_16x16x32_f16(A2P1, B2, zeroC, 0, 0, 0);
        f32x4 d2 = __builtin_amdgcn_mfma_f32_16x16x32_f16(A2P2, B2, zeroC, 0, 0, 0);
        d1 = __builtin_amdgcn_mfma_f32_16x16x32_f16(A1P1, B1, d1, 0, 0, 0);
        d2 = __builtin_amdgcn_mfma_f32_16x16x32_f16(A1P2, B1, d2, 0, 0, 0);

        float p1s[4], p2s[4];
        #pragma unroll
        for (int r = 0; r < 4; ++r)
            p1s[r] = sigm2(fmaf(-kL2E, d1[r], abk1[r]));
        #pragma unroll
        for (int r = 0; r < 4; ++r)
            p2s[r] = fmaf(am2, sigm2(fmaf(ank2, d2[r], abk2[r])), ams2);

        float hh[2];
        float cc[2] = {c0, c1};
        #pragma unroll
        for (int kk = 0; kk < 2; ++kk) {
            const float T1 = cLow ? p1s[kk + 2] : p1s[kk];
            const float R1 = swz8(T1);
            const float iv = cLow ? p1s[kk] : R1;
            const float fv = cLow ? R1 : p1s[kk + 2];
            const float T2 = cLow ? p2s[kk + 2] : p2s[kk];
            const float R2 = swz8(T2);
            const float gv = cLow ? p2s[kk] : R2;
            const float ov = cLow ? R2 : p2s[kk + 2];
            float cn = fmaf(fv, cc[kk], iv * gv);
            cn = active ? cn : 0.0f;
            cc[kk] = cn;
            const float tc = fmaf(2.0f, sigm2(-2.0f * kL2E * cn), -1.0f);
            hh[kk] = ov * tc;
        }
        c0 = cc[0]; c1 = cc[1];
        f16x2 hp = { (_Float16)hh[0], (_Float16)hh[1] };
        *(f16x2*)(hw + woff) = hp;
    };

    #pragma unroll 1
    for (int ib = 0; ib < kIB; ++ib) {
        const int sb  = ib * 8;
        const int sbm = sb & 15;                   // 0 or 8
        const int wb  = sbm * kSE;                 // write base (elems)
        const int rb0 = ((sbm ^ 8) + 7) * kSE;     // k==0 read slot (s-1)&15

        if (w < kNW - 1) {                         // ring-free check, per 8
            while (*dnc < sb - 8) __builtin_amdgcn_s_sleep(1);
            cbar();
        }
        #pragma unroll
        for (int k = 0; k < 8; ++k) {
            const int s = sb + k;
            if ((k & 1) == 0 && w > 0) {           // upstream-ready, per 2
                while (*upc < s) __builtin_amdgcn_s_sleep(1);
                cbar();
            }
            const int roff = (k == 0) ? rb0 : (wb + (k - 1) * kSE);
            const int woff = wb + k * kSE;
            const bool actA = ((unsigned)(s - lA) < (unsigned)kT);
            const bool actB = ((unsigned)(s - lB) < (unsigned)kT);

            lstep(A1P1a, A2P1a, A1P2a, A2P2a, abk1a, abk2a,
                  b1a, b2a, hwa, c0a, c1a, roff, woff, actA);
            lstep(A1P1b, A2P1b, A1P2b, A2P2b, abk1b, abk2b,
                  b1b, b2b, hwb, c0b, c1b, roff, woff, actB);

            if (w == 0) {                          // publish x(s+1), prefetch
                _Float16* xq = xw + woff;
                xq[0] = (_Float16)xg0;
                xq[1] = (_Float16)xg1;
                int tn = s + 2; if (tn > kT - 1) tn = kT - 1;
                float2 v = *(const float2*)(xg_ptr + (size_t)tn * kH);
                xg0 = v.x; xg1 = v.y;
            }
            if (k & 1) {                           // release, per 2
                cbar();
                if (lane == 0) *(volatile int*)&cnt[w] = s;
            }
        }
    }

    __syncthreads();

    // ---- head: layer-7 h(T-1) written at s=518 -> slot 6, lyr 8 ----
    if (w == kNW - 1) {
        const int bb = lane >> 3;
        const int r  = lane & 7;
        if (r < 6) {
            const bool  isP   = (r < 3);
            const float* wrow = isP ? (Wp + r * kH) : (Wo + (r - 3) * kH);
            float acc = isP ? bpos[r] : bori[r - 3];
            #pragma unroll
            for (int u = 0; u < kH; ++u)
                acc = fmaf((float)hb[6][kL][bb][u], wrow[u], acc);
            if (!isP) acc = fmaf(2.0f, sigm2(-2.0f * kL2E * acc), -1.0f);
            out[(size_t)(blockIdx.x * kNB + bb) * 6 + r] = acc;
        }
    }
}

extern "C" void kernel_launch(void* const* d_in, const int* in_sizes, int n_in,
                              void* d_out, int out_size, void* d_ws, size_t ws_size,
                              hipStream_t stream) {
    const float* x    = (const float*)d_in[0];
    const float* Wih  = (const float*)d_in[1];
    const float* Whh  = (const float*)d_in[2];
    const float* bih  = (const float*)d_in[3];
    const float* bhh  = (const float*)d_in[4];
    const float* Wp   = (const float*)d_in[5];
    const float* bpos = (const float*)d_in[6];
    const float* Wo   = (const float*)d_in[7];
    const float* bori = (const float*)d_in[8];
    float* out = (float*)d_out;

    const int B = in_sizes[0] / (kT * kH);   // 2048
    lstm_pair<<<dim3(B / kNB), dim3(256), 0, stream>>>(x, Wih, Whh, bih, bhh,
                                                       Wp, bpos, Wo, bori, out);
}

// Round 7
// 312.754 us; speedup vs baseline: 1.3673x; 1.3673x over previous
//
#include <hip/hip_runtime.h>
#include <math.h>

typedef _Float16 f16x8 __attribute__((ext_vector_type(8)));
typedef float    f32x4 __attribute__((ext_vector_type(4)));

constexpr int kT    = 512;   // sequence length
constexpr int kH    = 16;    // hidden
constexpr int kL    = 8;     // layers
constexpr int kG    = 64;    // gates
constexpr int kNB   = 8;     // batch per block
constexpr int kPad  = 24;    // f16 row stride (48 B)
constexpr int kRows = 9;     // 8 batch rows + permanent zero row
constexpr int kSlots= 16;    // ring depth (skew elasticity +-8)
constexpr int kLyr  = kL + 1;               // lyr 0 = x, lyr 1+l = layer l h
constexpr int kSE   = kLyr * kRows * kPad;  // f16 elems per slot (1944)
constexpr int kIters= 33;    // 33*16 = 528 steps >= kT+kL-1

constexpr float kL2E = 1.4426950408889634f;

__device__ __forceinline__ float sigm2(float z) {  // 1/(1+2^z)
    return __builtin_amdgcn_rcpf(1.0f + __builtin_amdgcn_exp2f(z));
}
__device__ __forceinline__ void cbar() { asm volatile("" ::: "memory"); }

// Row-permuted gate-packed LSTM. 8 waves = 8 layers, flag sync, 16-slot ring.
// Packing: P1 rows = gate + 4*unit for units 0-3 (K-left) / 4-7 (K-right),
// P2 same for units 8-15. D reg r of lane (n,q) = gate r, unit q(+4 if n>=8)
// (+8 for P2), batch n&7  =>  i,f,g,o all in-lane: no swizzle, no unpack.
__global__ __launch_bounds__(512, 2)
void lstm_rp(const float* __restrict__ x,
             const float* __restrict__ Wih, const float* __restrict__ Whh,
             const float* __restrict__ bih, const float* __restrict__ bhh,
             const float* __restrict__ Wp,  const float* __restrict__ bpos,
             const float* __restrict__ Wo,  const float* __restrict__ bori,
             float* __restrict__ out)
{
    const int tid  = threadIdx.x;
    const int l    = tid >> 6;
    const int lane = tid & 63;
    const int n    = lane & 15;
    const int q    = lane >> 4;
    const int bn   = n & 7;
    const bool cLow = (n < 8);
    const bool bact = ((q >> 1) == (n >> 3));   // lane holds nonzero B data

    __shared__ __align__(16) _Float16 hb[kSlots][kLyr][kRows][kPad];  // 62208 B
    __shared__ int cnt[kL];

    {   // zero-init LDS; counters to -1
        int* hz = (int*)&hb[0][0][0][0];
        for (int i = tid; i < (int)(sizeof(hb) / 4); i += 512) hz[i] = 0;
        if (tid < kL) cnt[tid] = -1;
    }

    // ---- A fragments, row-permuted: A[m=n][k=q*8+j] ----
    // gate = n&3, unit = tile + (n>>2) + (q>=2 ? 4 : 0); W row = gate*16+unit
    auto loadA = [&](const float* W, int tile) -> f16x8 {
        const int unit = tile + (n >> 2) + ((q >= 2) ? 4 : 0);
        const int row  = (n & 3) * 16 + unit;
        const float* src = W + (size_t)l * kG * kH + row * kH + (q & 1) * 8;
        f16x8 a;
        #pragma unroll
        for (int j = 0; j < 8; ++j) a[j] = (_Float16)src[j];
        return a;
    };
    const f16x8 A1P1 = loadA(Wih, 0), A2P1 = loadA(Whh, 0);
    const f16x8 A1P2 = loadA(Wih, 8), A2P2 = loadA(Whh, 8);

    // ---- biases folded into activation arg; gate r is compile-time per reg ----
    // D reg r: gate r, unit u_t, batch bn.  scale: r==2 (g) -> -2*L2E else -L2E
    const int u1 = (cLow ? q : 4 + q);       // P1 unit; P2 = u1+8
    float ab1[4], ab2[4];
    #pragma unroll
    for (int r = 0; r < 4; ++r) {
        const float sc = (r == 2) ? (-2.0f * kL2E) : (-kL2E);
        const int g1 = l * kG + r * 16 + u1;
        const int g2 = l * kG + r * 16 + u1 + 8;
        ab1[r] = sc * (bih[g1] + bhh[g1]);
        ab2[r] = sc * (bih[g2] + bhh[g2]);
    }

    // ---- LDS base pointers (slot 0; ring slot adds kSE elems) ----
    const int boff = (bact ? bn * kPad : 8 * kPad) + (q & 1) * 8;
    const _Float16* b1b = &hb[0][l    ][0][0] + boff;   // v-input (x or h_{l-1})
    const _Float16* b2b = &hb[0][l + 1][0][0] + boff;   // own h
    _Float16* hw1 = &hb[0][l + 1][bn][u1];              // P1 h element
    _Float16* hw2 = &hb[0][l + 1][bn][u1 + 8];          // P2 h element
    _Float16* xwb = &hb[0][0][lane >> 3][(lane & 7) * 2];

    // ---- x staging (wave 0): prime x(0) -> slot 15, prefetch x(1) ----
    const float* xg_ptr =
        x + ((size_t)(blockIdx.x * kNB + (lane >> 3)) * kT) * kH + (lane & 7) * 2;
    float xg0 = 0.f, xg1 = 0.f;
    if (l == 0) {
        float2 v0 = *(const float2*)(xg_ptr);
        hb[15][0][lane >> 3][(lane & 7) * 2]     = (_Float16)v0.x;
        hb[15][0][lane >> 3][(lane & 7) * 2 + 1] = (_Float16)v0.y;
        float2 v1 = *(const float2*)(xg_ptr + kH);
        xg0 = v1.x; xg1 = v1.y;
    }

    float c1 = 0.f, c2 = 0.f;
    __syncthreads();    // init visible; last barrier until the head

    const f32x4 zeroC = {0.f, 0.f, 0.f, 0.f};
    volatile const int* upc = (l > 0)      ? &cnt[l - 1] : nullptr;
    volatile const int* dnc = (l < kL - 1) ? &cnt[l + 1] : nullptr;

    for (int it = 0; it < kIters; ++it) {
        const int sb = it * 16;
        #pragma unroll
        for (int k = 0; k < 16; ++k) {
            const int s = sb + k;

            // ---- sync: upstream-ready (per 2), ring-free (per 8) ----
            if ((k & 1) == 0 && l > 0) {
                while (*upc < s) __builtin_amdgcn_s_sleep(1);
                cbar();
            }
            if ((k == 0 || k == 8) && l < kL - 1) {
                const int need = (k == 0) ? (sb - 8) : sb;
                while (*dnc < need) __builtin_amdgcn_s_sleep(1);
                cbar();
            }

            const int  t      = s - l;
            const bool active = ((unsigned)t < (unsigned)kT);
            const int  rs     = (k + 15) & 15;             // read slot (s-1)
            const int  roff   = rs * kSE;
            const int  woff   = k * kSE;

            const f16x8 B1 = *(const f16x8*)(b1b + roff);
            const f16x8 B2 = *(const f16x8*)(b2b + roff);

            f32x4 d1 = __builtin_amdgcn_mfma_f32_16x16x32_f16(A2P1, B2, zeroC, 0, 0, 0);
            f32x4 d2 = __builtin_amdgcn_mfma_f32_16x16x32_f16(A2P2, B2, zeroC, 0, 0, 0);
            d1 = __builtin_amdgcn_mfma_f32_16x16x32_f16(A1P1, B1, d1, 0, 0, 0);
            d2 = __builtin_amdgcn_mfma_f32_16x16x32_f16(A1P2, B1, d2, 0, 0, 0);

            // ---- in-lane gate update, tile P1 (unit u1) ----
            {
                const float iv = sigm2(fmaf(-kL2E,        d1[0], ab1[0]));
                const float fv = sigm2(fmaf(-kL2E,        d1[1], ab1[1]));
                const float gv = fmaf(2.f, sigm2(fmaf(-2.f * kL2E, d1[2], ab1[2])), -1.f);
                const float ov = sigm2(fmaf(-kL2E,        d1[3], ab1[3]));
                float cn = fmaf(fv, c1, iv * gv);
                cn = active ? cn : 0.0f;
                c1 = cn;
                const float tc = fmaf(2.f, sigm2(-2.f * kL2E * cn), -1.f);
                hw1[woff] = (_Float16)(ov * tc);
            }
            // ---- tile P2 (unit u1+8) ----
            {
                const float iv = sigm2(fmaf(-kL2E,        d2[0], ab2[0]));
                const float fv = sigm2(fmaf(-kL2E,        d2[1], ab2[1]));
                const float gv = fmaf(2.f, sigm2(fmaf(-2.f * kL2E, d2[2], ab2[2])), -1.f);
                const float ov = sigm2(fmaf(-kL2E,        d2[3], ab2[3]));
                float cn = fmaf(fv, c2, iv * gv);
                cn = active ? cn : 0.0f;
                c2 = cn;
                const float tc = fmaf(2.f, sigm2(-2.f * kL2E * cn), -1.f);
                hw2[woff] = (_Float16)(ov * tc);
            }

            if (l == 0) {                                   // publish x(s+1)
                _Float16* xw = xwb + woff;
                xw[0] = (_Float16)xg0;
                xw[1] = (_Float16)xg1;
                int tn = s + 2; if (tn > kT - 1) tn = kT - 1;
                float2 v = *(const float2*)(xg_ptr + (size_t)tn * kH);
                xg0 = v.x; xg1 = v.y;
            }

            if (k & 1) {                                    // release, per 2
                cbar();
                if (lane == 0) *(volatile int*)&cnt[l] = s;
            }
        }
    }

    __syncthreads();

    // ---- head: layer-7 h(T-1) written at s=518 -> slot 6, lyr 8 ----
    if (l == kL - 1) {
        const int bb = lane >> 3;
        const int r  = lane & 7;
        if (r < 6) {
            const bool  isP   = (r < 3);
            const float* wrow = isP ? (Wp + r * kH) : (Wo + (r - 3) * kH);
            float acc = isP ? bpos[r] : bori[r - 3];
            #pragma unroll
            for (int u = 0; u < kH; ++u)
                acc = fmaf((float)hb[6][kL][bb][u], wrow[u], acc);
            if (!isP) acc = fmaf(2.f, sigm2(-2.f * kL2E * acc), -1.f);
            out[(size_t)(blockIdx.x * kNB + bb) * 6 + r] = acc;
        }
    }
}

extern "C" void kernel_launch(void* const* d_in, const int* in_sizes, int n_in,
                              void* d_out, int out_size, void* d_ws, size_t ws_size,
                              hipStream_t stream) {
    const float* x    = (const float*)d_in[0];
    const float* Wih  = (const float*)d_in[1];
    const float* Whh  = (const float*)d_in[2];
    const float* bih  = (const float*)d_in[3];
    const float* bhh  = (const float*)d_in[4];
    const float* Wp   = (const float*)d_in[5];
    const float* bpos = (const float*)d_in[6];
    const float* Wo   = (const float*)d_in[7];
    const float* bori = (const float*)d_in[8];
    float* out = (float*)d_out;

    const int B = in_sizes[0] / (kT * kH);   // 2048
    lstm_rp<<<dim3(B / kNB), dim3(512), 0, stream>>>(x, Wih, Whh, bih, bhh,
                                                     Wp, bpos, Wo, bori, out);
}

// Round 8
// 300.066 us; speedup vs baseline: 1.4252x; 1.0423x over previous
//
#include <hip/hip_runtime.h>
#include <math.h>

typedef _Float16 f16x8 __attribute__((ext_vector_type(8)));
typedef _Float16 f16x2 __attribute__((ext_vector_type(2)));
typedef float    f32x4 __attribute__((ext_vector_type(4)));

constexpr int kT    = 512;   // sequence length
constexpr int kH    = 16;    // hidden
constexpr int kL    = 8;     // layers
constexpr int kG    = 64;    // gates
constexpr int kNB   = 8;     // batch per block
constexpr int kPad  = 24;    // f16 row stride (48 B)
constexpr int kRows = 9;     // 8 batch rows + permanent zero row
constexpr int kSlots= 16;    // ring depth
constexpr int kLyr  = kL + 1;               // lyr 0 = x, lyr 1+l = layer l h
constexpr int kSE   = kLyr * kRows * kPad;  // f16 elems per slot (1944)
constexpr int kIters= 33;    // 528 steps >= kT+kL-1
constexpr int kLastS= kIters * 16 - 1;      // 527 (release cap)

constexpr float kL2E = 1.4426950408889634f;

__device__ __forceinline__ float ex2(float w)  { return __builtin_amdgcn_exp2f(w); }
__device__ __forceinline__ float rcp1p(float e){ return __builtin_amdgcn_rcpf(1.0f + e); }
__device__ __forceinline__ void  cbar()        { asm volatile("" ::: "memory"); }

// Software-pipelined recurrence (round-8):
//  - input-half GEMM dIn(s+1)=MFMA(A1,B1(s+1),bias) computed during step s
//  - B2(s+1) read issued right after h(s) write (latency hidden by dIn MFMAs)
//  - activation scales folded into A; c-recursion in -2*log2e-scaled domain
//  - unit-interleaved h layout: pos(u) = 2*(u&7)+(u>>3) -> lane's 2 h adjacent
// Tile math: tile T covers units q + 4*(n>>3) + 8T; D reg r = gate r (i,f,g,o)
__global__ __launch_bounds__(512, 2)
void lstm_sp(const float* __restrict__ x,
             const float* __restrict__ Wih, const float* __restrict__ Whh,
             const float* __restrict__ bih, const float* __restrict__ bhh,
             const float* __restrict__ Wp,  const float* __restrict__ bpos,
             const float* __restrict__ Wo,  const float* __restrict__ bori,
             float* __restrict__ out)
{
    const int tid  = threadIdx.x;
    const int l    = tid >> 6;
    const int lane = tid & 63;
    const int n    = lane & 15;
    const int q    = lane >> 4;
    const int bn   = n & 7;
    const bool bact = ((q >> 1) == (n >> 3));

    __shared__ __align__(16) _Float16 hb[kSlots][kLyr][kRows][kPad];  // 62208 B
    __shared__ int cnt[kL];

    {   // zero-init LDS; counters to -1
        int* hz = (int*)&hb[0][0][0][0];
        for (int i = tid; i < (int)(sizeof(hb) / 4); i += 512) hz[i] = 0;
        if (tid < kL) cnt[tid] = -1;
    }
    __syncthreads();

    // ---- A fragments, scaled + column-permuted ----
    // A row m=n: W row = (n&3)*16 + (n>>2) + 4*(q>>1) + 8T
    // W col for j: u = (q&1)*4 + (j>>1) + 8*(j&1)   (pos-perm inverse)
    // scale: gate (n&3)==2 (g) -> -2*L2E else -L2E
    const float asc = ((n & 3) == 2) ? (-2.0f * kL2E) : (-kL2E);
    auto loadA = [&](const float* W, int T) -> f16x8 {
        const int wrow = (n & 3) * 16 + (n >> 2) + 4 * (q >> 1) + 8 * T;
        const float* src = W + (size_t)l * kG * kH + wrow * kH;
        f16x8 a;
        #pragma unroll
        for (int j = 0; j < 8; ++j) {
            const int u = (q & 1) * 4 + (j >> 1) + 8 * (j & 1);
            a[j] = (_Float16)(asc * src[u]);
        }
        return a;
    };
    const f16x8 A1T0 = loadA(Wih, 0), A2T0 = loadA(Whh, 0);
    const f16x8 A1T1 = loadA(Wih, 1), A2T1 = loadA(Whh, 1);

    // ---- scaled bias as MFMA C-init: reg r = gate r, unit q+4*(n>>3)+8T ----
    const int u0 = q + 4 * (n >> 3);          // tile-0 unit; tile 1 = u0+8
    f32x4 bias0, bias1;
    #pragma unroll
    for (int r = 0; r < 4; ++r) {
        const float sc = (r == 2) ? (-2.0f * kL2E) : (-kL2E);
        const int g0 = l * kG + r * 16 + u0;
        bias0[r] = sc * (bih[g0] + bhh[g0]);
        bias1[r] = sc * (bih[g0 + 8] + bhh[g0 + 8]);
    }

    // ---- LDS pointers ----
    const int boff = (bact ? bn * kPad : 8 * kPad) + (q & 1) * 8;
    const _Float16* b1b = &hb[0][l    ][0][0] + boff;     // v-input (x / h_{l-1})
    const _Float16* b2b = &hb[0][l + 1][0][0] + boff;     // own h
    _Float16* hw  = &hb[0][l + 1][bn][2 * u0];            // packed h (b32)
    _Float16* xw  = &hb[0][0][lane >> 3][2 * (lane & 7)]; // packed x (b32)

    // ---- x staging (wave 0): lane covers batch lane>>3, units a & a+8 ----
    const int xa = lane & 7;
    const float* xg_ptr =
        x + ((size_t)(blockIdx.x * kNB + (lane >> 3)) * kT) * kH;
    float xg0 = 0.f, xg1 = 0.f;
    if (l == 0) {
        // prime x(0)->slot 0, x(1)->slot 1; regs hold x(2)
        #pragma unroll
        for (int t = 0; t < 2; ++t) {
            f16x2 xp = { (_Float16)xg_ptr[t * kH + xa],
                         (_Float16)xg_ptr[t * kH + xa + 8] };
            *(f16x2*)(xw + t * kSE) = xp;
        }
        xg0 = xg_ptr[2 * kH + xa];
        xg1 = xg_ptr[2 * kH + xa + 8];
    }

    // ---- prime: B2(0) (zeros), dIn(0) from B1(0) (zeros or x(0)) ----
    f16x8 B2r = *(const f16x8*)(b2b);
    {
        const f16x8 B1p = *(const f16x8*)(b1b);
        // (defer MFMA until after reads settle; compiler orders via lgkmcnt)
        // dIn set below
    }
    const f16x8 B1p = *(const f16x8*)(b1b);
    f32x4 dIn0 = __builtin_amdgcn_mfma_f32_16x16x32_f16(A1T0, B1p, bias0, 0, 0, 0);
    f32x4 dIn1 = __builtin_amdgcn_mfma_f32_16x16x32_f16(A1T1, B1p, bias1, 0, 0, 0);

    float c0 = 0.f, c1 = 0.f;     // scaled cell state c' = -2*L2E*c

    volatile const int* upc = (l > 0)      ? &cnt[l - 1] : nullptr;
    volatile const int* dnc = (l < kL - 1) ? &cnt[l + 1] : nullptr;

    #pragma unroll 1
    for (int it = 0; it < kIters; ++it) {
        const int sb = it * 16;
        #pragma unroll
        for (int k = 0; k < 16; ++k) {
            const int s = sb + k;

            if ((k & 1) == 0 && l > 0) {             // upstream-ready, per 2
                int need = s + 1; if (need > kLastS) need = kLastS;
                while (*upc < need) __builtin_amdgcn_s_sleep(1);
                cbar();
            }
            if ((k == 0 || k == 8) && l < kL - 1) {  // ring-free, per 8
                const int need = (k == 0) ? (sb - 8) : sb;
                while (*dnc < need) __builtin_amdgcn_s_sleep(1);
                cbar();
            }

            const int  slot1  = ((k + 1) & 15) * kSE;   // step s+1 slot
            const int  slot2  = ((k + 2) & 15) * kSE;
            const bool active = ((unsigned)(s - l) < (unsigned)kT);

            // B1(s+1) early (consumed by dIn MFMAs at body end)
            const f16x8 B1n = *(const f16x8*)(b1b + slot1);

            // recurrent half: d = A2*h(s-1) + dIn(s)  [chain head]
            f32x4 d0 = __builtin_amdgcn_mfma_f32_16x16x32_f16(A2T0, B2r, dIn0, 0, 0, 0);
            f32x4 d1 = __builtin_amdgcn_mfma_f32_16x16x32_f16(A2T1, B2r, dIn1, 0, 0, 0);

            // in-lane cell update (args already scaled+biased)
            float h0, h1;
            {
                const float si = rcp1p(ex2(d0[0]));
                const float sf = rcp1p(ex2(d0[1]));
                const float sg = rcp1p(ex2(d0[2]));
                const float so = rcp1p(ex2(d0[3]));
                const float tgp = fmaf(-4.0f * kL2E, sg, 2.0f * kL2E);
                float cn = fmaf(sf, c0, si * tgp);
                cn = active ? cn : 0.0f;
                c0 = cn;
                h0 = so * fmaf(2.0f, rcp1p(ex2(cn)), -1.0f);
            }
            {
                const float si = rcp1p(ex2(d1[0]));
                const float sf = rcp1p(ex2(d1[1]));
                const float sg = rcp1p(ex2(d1[2]));
                const float so = rcp1p(ex2(d1[3]));
                const float tgp = fmaf(-4.0f * kL2E, sg, 2.0f * kL2E);
                float cn = fmaf(sf, c1, si * tgp);
                cn = active ? cn : 0.0f;
                c1 = cn;
                h1 = so * fmaf(2.0f, rcp1p(ex2(cn)), -1.0f);
            }

            // publish h(s) -> slot s+1 (adjacent positions, single b32)
            f16x2 hp = { (_Float16)h0, (_Float16)h1 };
            *(f16x2*)(hw + slot1) = hp;

            if (l == 0) {                            // publish x(s+2), prefetch
                f16x2 xp = { (_Float16)xg0, (_Float16)xg1 };
                *(f16x2*)(xw + slot2) = xp;
                int tn = s + 3; if (tn > kT - 1) tn = kT - 1;
                xg0 = xg_ptr[(size_t)tn * kH + xa];
                xg1 = xg_ptr[(size_t)tn * kH + xa + 8];
            }

            // B2(s+1) = own h(s) just written (in-order DS); latency hidden
            B2r = *(const f16x8*)(b2b + slot1);

            // input half for step s+1 (off-chain), bias rides C
            dIn0 = __builtin_amdgcn_mfma_f32_16x16x32_f16(A1T0, B1n, bias0, 0, 0, 0);
            dIn1 = __builtin_amdgcn_mfma_f32_16x16x32_f16(A1T1, B1n, bias1, 0, 0, 0);

            if (k & 1) {                             // release, per 2
                cbar();
                if (lane == 0) *(volatile int*)&cnt[l] = s;
            }
        }
    }

    __syncthreads();

    // ---- head: layer-7 h(T-1) written at s=518 -> slot (518+1)&15 = 7 ----
    if (l == kL - 1) {
        const int bb = lane >> 3;
        const int r  = lane & 7;
        if (r < 6) {
            const bool  isP   = (r < 3);
            const float* wrow = isP ? (Wp + r * kH) : (Wo + (r - 3) * kH);
            float acc = isP ? bpos[r] : bori[r - 3];
            #pragma unroll
            for (int u = 0; u < kH; ++u) {
                const int p = 2 * (u & 7) + (u >> 3);
                acc = fmaf((float)hb[7][kL][bb][p], wrow[u], acc);
            }
            if (!isP) acc = fmaf(2.0f, rcp1p(ex2(-2.0f * kL2E * acc)), -1.0f);
            out[(size_t)(blockIdx.x * kNB + bb) * 6 + r] = acc;
        }
    }
}

extern "C" void kernel_launch(void* const* d_in, const int* in_sizes, int n_in,
                              void* d_out, int out_size, void* d_ws, size_t ws_size,
                              hipStream_t stream) {
    const float* x    = (const float*)d_in[0];
    const float* Wih  = (const float*)d_in[1];
    const float* Whh  = (const float*)d_in[2];
    const float* bih  = (const float*)d_in[3];
    const float* bhh  = (const float*)d_in[4];
    const float* Wp   = (const float*)d_in[5];
    const float* bpos = (const float*)d_in[6];
    const float* Wo   = (const float*)d_in[7];
    const float* bori = (const float*)d_in[8];
    float* out = (float*)d_out;

    const int B = in_sizes[0] / (kT * kH);   // 2048
    lstm_sp<<<dim3(B / kNB), dim3(512), 0, stream>>>(x, Wih, Whh, bih, bhh,
                                                     Wp, bpos, Wo, bori, out);
}